// Round 2
// baseline (434.752 us; speedup 1.0000x reference)
//
#include <hip/hip_runtime.h>
#include <math.h>

// RoPE over x[4,32,4096,128] fp32. out[2i] = cos*x[2i]-sin*x[2i+1]; out[2i+1] = sin*x[2i]+cos*x[2i+1]
// a(s,i) = pos[s] * theta^(-i/64), i in [0,64).
//
// v2 structure:
//   Kernel 1: build a [4096][32] float4 table (c0,s0,c1,s1) in d_ws (2 MiB, L2-resident).
//             Angles depend only on (s, pair) and are reused 128x across (b,h) slices,
//             so all hot-path transcendentals are redundant.
//   Kernel 2: pure streaming rotate. 4 float4 per thread at stride T (T is a multiple of
//             the 131072-float4 table period, so ONE table load serves all 4), nontemporal
//             loads/stores for the 512 MiB stream so the table stays L2-hot.
//
// NOTE: __builtin_nontemporal_* requires a clang vector type, not HIP_vector_type
// (float4). Use a native ext_vector_type alias for the streaming paths.
//
// Memory floor: 512 MiB @ ~6.3 TB/s => ~85 us.

typedef float f32x4 __attribute__((ext_vector_type(4)));

#define THETA_LOG2_OVER_HALF 0.20762050593046013f   // log2(10000)/64
#define FREQ_STEP 0.8659643233600653f               // 10000^(-1/64)

#define SEQ 4096
#define ROW_F4 32                       // 128 floats per row = 32 float4
#define TABLE_F4 (SEQ * ROW_F4)         // 131072 float4
#define TABLE_BYTES ((size_t)TABLE_F4 * 16)   // 2 MiB

// ---------------- Kernel 1: trig table ----------------
// table[s*32 + j] = (cos a0, sin a0, cos a1, sin a1), pairs i0=2j, i0+1.
__global__ __launch_bounds__(256) void rope_table_kernel(
    const int* __restrict__ token_positions,
    f32x4* __restrict__ table)
{
    int idx = blockIdx.x * blockDim.x + threadIdx.x;
    if (idx >= TABLE_F4) return;
    int s = idx >> 5;
    int j = idx & 31;

    float p  = (float)token_positions[s];
    float f0 = exp2f(-THETA_LOG2_OVER_HALF * (float)(2 * j));
    float f1 = f0 * FREQ_STEP;

    float s0, c0, s1, c1;
    sincosf(p * f0, &s0, &c0);   // precise trig: better absmax than __sinf at args up to ~4095 rad
    sincosf(p * f1, &s1, &c1);

    f32x4 e;
    e.x = c0; e.y = s0; e.z = c1; e.w = s1;
    table[idx] = e;
}

// ---------------- Kernel 2: streaming rotate, 4 float4/thread ----------------
__global__ __launch_bounds__(256) void rope_f32_table4_kernel(
    const f32x4* __restrict__ x,
    const f32x4* __restrict__ table,
    f32x4* __restrict__ out,
    int n4)
{
    int T = n4 >> 2;                                  // total threads
    int t = blockIdx.x * blockDim.x + threadIdx.x;
    if (t >= T) return;

    // T is a multiple of TABLE_F4 (guarded in launcher), so all 4 offsets
    // share one table entry: (t + k*T) mod TABLE_F4 == t mod TABLE_F4.
    f32x4 cs = table[t & (TABLE_F4 - 1)];

    // Issue all 4 nontemporal loads up front: 4 outstanding VMEM ops per lane.
    f32x4 v0 = __builtin_nontemporal_load(&x[t]);
    f32x4 v1 = __builtin_nontemporal_load(&x[t +     T]);
    f32x4 v2 = __builtin_nontemporal_load(&x[t + 2 * T]);
    f32x4 v3 = __builtin_nontemporal_load(&x[t + 3 * T]);

    f32x4 r;
    r.x = cs.x * v0.x - cs.y * v0.y;
    r.y = cs.y * v0.x + cs.x * v0.y;
    r.z = cs.z * v0.z - cs.w * v0.w;
    r.w = cs.w * v0.z + cs.z * v0.w;
    __builtin_nontemporal_store(r, &out[t]);

    r.x = cs.x * v1.x - cs.y * v1.y;
    r.y = cs.y * v1.x + cs.x * v1.y;
    r.z = cs.z * v1.z - cs.w * v1.w;
    r.w = cs.w * v1.z + cs.z * v1.w;
    __builtin_nontemporal_store(r, &out[t + T]);

    r.x = cs.x * v2.x - cs.y * v2.y;
    r.y = cs.y * v2.x + cs.x * v2.y;
    r.z = cs.z * v2.z - cs.w * v2.w;
    r.w = cs.w * v2.z + cs.z * v2.w;
    __builtin_nontemporal_store(r, &out[t + 2 * T]);

    r.x = cs.x * v3.x - cs.y * v3.y;
    r.y = cs.y * v3.x + cs.x * v3.y;
    r.z = cs.z * v3.z - cs.w * v3.w;
    r.w = cs.w * v3.z + cs.z * v3.w;
    __builtin_nontemporal_store(r, &out[t + 3 * T]);
}

// ---------------- Fallback: original inline-trig kernel ----------------
__global__ __launch_bounds__(256) void rope_f32_kernel(
    const float4* __restrict__ x,
    const int* __restrict__ token_positions,
    float4* __restrict__ out,
    int n4)
{
    int t = blockIdx.x * blockDim.x + threadIdx.x;
    if (t >= n4) return;

    int s  = (t >> 5) & 4095;
    int i0 = (t & 31) * 2;

    float p  = (float)token_positions[s];
    float f0 = exp2f(-THETA_LOG2_OVER_HALF * (float)i0);
    float f1 = f0 * FREQ_STEP;

    float a0 = p * f0, a1 = p * f1;
    float s0 = __sinf(a0), c0 = __cosf(a0);
    float s1 = __sinf(a1), c1 = __cosf(a1);

    float4 v = x[t];
    float4 r;
    r.x = c0 * v.x - s0 * v.y;
    r.y = s0 * v.x + c0 * v.y;
    r.z = c1 * v.z - s1 * v.w;
    r.w = s1 * v.z + c1 * v.w;
    out[t] = r;
}

extern "C" void kernel_launch(void* const* d_in, const int* in_sizes, int n_in,
                              void* d_out, int out_size, void* d_ws, size_t ws_size,
                              hipStream_t stream) {
    const int* token_positions = (const int*)d_in[1];

    int n4 = out_size / 4;   // out_size is in floats; 16,777,216 float4s

    if (ws_size >= TABLE_BYTES && n4 >= TABLE_F4 && (n4 % (TABLE_F4 * 4)) == 0) {
        f32x4* table = (f32x4*)d_ws;

        rope_table_kernel<<<dim3(TABLE_F4 / 256), dim3(256), 0, stream>>>(
            token_positions, table);

        int T = n4 >> 2;     // 4,194,304 threads; multiple of TABLE_F4 and of 256
        rope_f32_table4_kernel<<<dim3(T / 256), dim3(256), 0, stream>>>(
            (const f32x4*)d_in[0], table, (f32x4*)d_out, n4);
    } else {
        int grid = (n4 + 255) / 256;
        rope_f32_kernel<<<grid, dim3(256), 0, stream>>>(
            (const float4*)d_in[0], token_positions, (float4*)d_out, n4);
    }
}